// Round 2
// baseline (6168.735 us; speedup 1.0000x reference)
//
#include <hip/hip_runtime.h>
#include <math.h>

#define V_   8
#define H_   256
#define W_   256
#define L_   32
#define HID_ 64
#define NC_  64
#define NF_  64
#define R_   1024
#define IND_ 41              // 3 + 32 + 3 + 3
#define HW_  (H_*W_)

// ---------------------------------------------------------------- P = K @ E
__global__ void k_computeP(const float* __restrict__ Km,
                           const float* __restrict__ Em,
                           float* __restrict__ Pm) {
    int t = threadIdx.x;
    if (t >= V_ * 12) return;
    int v = t / 12, e = t - v * 12, row = e >> 2, col = e & 3;
    float acc = 0.f;
    #pragma unroll
    for (int k = 0; k < 3; ++k)
        acc += Km[v * 9 + row * 3 + k] * Em[v * 12 + k * 4 + col];
    Pm[v * 12 + row * 4 + col] = acc;
}

// ------------------------------------------- transpose weights: column-major
// out layout: [cW1T 64*44][cW2T 64*64][fW1T 64*44][fW2T 64*64]
__global__ void k_packW(const float* __restrict__ W1c, const float* __restrict__ W2c,
                        const float* __restrict__ W1f, const float* __restrict__ W2f,
                        float* __restrict__ out) {
    int t = threadIdx.x + blockIdx.x * blockDim.x;
    if (t < 64 * 41) {
        int j = t / 41, k = t - j * 41;
        out[j * 44 + k]               = W1c[k * 64 + j];
        out[6912 + j * 44 + k]        = W1f[k * 64 + j];
    }
    if (t < 64 * 64) {
        int j = t >> 6, k = t & 63;
        out[2816 + j * 64 + k]        = W2c[k * 64 + j];
        out[9728 + j * 64 + k]        = W2f[k * 64 + j];
    }
}

// -------------------------- pack 32 feature channels to pixel-major [V][HW][32]
__global__ __launch_bounds__(256) void k_packF(const float* __restrict__ fea,
                                               float* __restrict__ pk, int FS) {
    __shared__ float tile[32][65];
    const int xb = blockIdx.x * 64, y = blockIdx.y, v = blockIdx.z;
    const int t = threadIdx.x;
    #pragma unroll
    for (int step = 0; step < 8; ++step) {
        int c = step * 4 + (t >> 6);
        int x = t & 63;
        tile[c][x] = fea[((size_t)(v * 2 * L_ + FS + c)) * HW_ + y * W_ + xb + x];
    }
    __syncthreads();
    #pragma unroll
    for (int step = 0; step < 8; ++step) {
        int x = step * 8 + (t >> 5);
        int c = t & 31;
        pk[((size_t)v * HW_ + y * W_ + xb + x) * 32 + c] = tile[c][x];
    }
}

// ------------------------------------------------- per-point gather + MLP
// One wave (64 lanes) per point-sample; lane = hidden channel index.
template <int S, int FS, bool FINE, bool PACKED>
__global__ __launch_bounds__(256) void k_points(
    const float* __restrict__ ray, const float* __restrict__ Pm,
    const float* __restrict__ cam, const float* __restrict__ shp,
    const float* __restrict__ msk, const float* __restrict__ img,
    const float* __restrict__ fea, const float* __restrict__ pk,
    const float* __restrict__ WT1, const float* __restrict__ WT2,
    const float* __restrict__ W1, const float* __restrict__ b1,
    const float* __restrict__ W2, const float* __restrict__ b2,
    const float* __restrict__ Wd, const float* __restrict__ bd,
    const float* __restrict__ Wb, const float* __restrict__ bb,
    const float* __restrict__ deptharr,
    float* __restrict__ odens, float* __restrict__ orgb) {

    const int wid  = (int)((blockIdx.x * blockDim.x + threadIdx.x) >> 6);
    const int lane = threadIdx.x & 63;
    const int r = wid / S, s = wid - r * S;

    // register-cached weight columns for this lane's hidden channel
    float w1c[IND_];
    float w2c[HID_];
    if (PACKED) {
        const float4* w1v = (const float4*)(WT1 + lane * 44);
        #pragma unroll
        for (int k4 = 0; k4 < 10; ++k4) {
            float4 q = w1v[k4];
            w1c[k4*4+0] = q.x; w1c[k4*4+1] = q.y; w1c[k4*4+2] = q.z; w1c[k4*4+3] = q.w;
        }
        w1c[40] = WT1[lane * 44 + 40];
        const float4* w2v = (const float4*)(WT2 + lane * 64);
        #pragma unroll
        for (int k4 = 0; k4 < 16; ++k4) {
            float4 q = w2v[k4];
            w2c[k4*4+0] = q.x; w2c[k4*4+1] = q.y; w2c[k4*4+2] = q.z; w2c[k4*4+3] = q.w;
        }
    } else {
        #pragma unroll
        for (int k = 0; k < IND_; ++k) w1c[k] = W1[k * HID_ + lane];
        #pragma unroll
        for (int k = 0; k < HID_; ++k) w2c[k] = W2[k * HID_ + lane];
    }
    const float b1j = b1[lane], b2j = b2[lane], wbj = Wb[lane];
    const float wd0 = Wd[lane], wd1 = Wd[HID_ + lane];
    const float bdv = bd[0], bbv = bb[0];

    const float ox = ray[r*8+0], oy = ray[r*8+1], oz = ray[r*8+2];
    const float dx = ray[r*8+3], dy = ray[r*8+4], dz = ray[r*8+5];
    const float nv = ray[r*8+6], fv = ray[r*8+7];

    float depth;
    if (FINE) depth = deptharr[wid];
    else      depth = nv + (fv - nv) * ((s + 0.5f) / (float)S);

    const float px = ox + dx*depth, py = oy + dy*depth, pz = oz + dz*depth;
    const float dn = sqrtf(dx*dx + dy*dy + dz*dz);
    const float rdx = -dx/dn, rdy = -dy/dn, rdz = -dz/dn;   // ray_dirc = -d/|d|

    float sumh = 0.f, sumq = 0.f, hullsum = 0.f;
    float logit[V_], rgbv0[V_], rgbv1[V_], rgbv2[V_];

    #pragma unroll
    for (int v = 0; v < V_; ++v) {
        const float* Pv = Pm + v * 12;
        float q0 = Pv[0]*px + Pv[1]*py + Pv[2]*pz  + Pv[3];
        float q1 = Pv[4]*px + Pv[5]*py + Pv[6]*pz  + Pv[7];
        float q2 = Pv[8]*px + Pv[9]*py + Pv[10]*pz + Pv[11];
        float inv = 1.0f / (q2 + 1e-6f);
        float u = q0 * inv, w = q1 * inv;
        // wh = source_shape[:, ::-1]  -> (W, H)
        float gx = 2.0f * (u / shp[v*2+1]) - 1.0f;
        float gy = 2.0f * (w / shp[v*2+0]) - 1.0f;
        float sx = (gx + 1.0f) * ((float)W_ * 0.5f) - 0.5f;
        float sy = (gy + 1.0f) * ((float)H_ * 0.5f) - 0.5f;
        float x0f = floorf(sx), y0f = floorf(sy);
        float fx = sx - x0f, fy = sy - y0f;

        int offp[4]; float wt[4];
        {
            float xs[2] = {x0f, x0f + 1.f}, ys[2] = {y0f, y0f + 1.f};
            float wxs[2] = {1.f - fx, fx},  wys[2] = {1.f - fy, fy};
            #pragma unroll
            for (int t = 0; t < 4; ++t) {
                float xf = xs[t & 1], yf = ys[t >> 1];
                bool val = (xf >= 0.f) && (xf <= (float)(W_-1)) &&
                           (yf >= 0.f) && (yf <= (float)(H_-1));
                int xi = (int)fminf(fmaxf(xf, 0.f), (float)(W_-1));
                int yi = (int)fminf(fmaxf(yf, 0.f), (float)(H_-1));
                offp[t] = yi * W_ + xi;
                wt[t] = wxs[t & 1] * wys[t >> 1] * (val ? 1.f : 0.f);
            }
        }
        // mask sample (uniform-address broadcast loads)
        const float* mb = msk + v * HW_;
        hullsum += wt[0]*mb[offp[0]] + wt[1]*mb[offp[1]]
                 + wt[2]*mb[offp[2]] + wt[3]*mb[offp[3]];
        // rgb sample (uniform-address broadcast loads)
        float rv0 = 0.f, rv1 = 0.f, rv2 = 0.f;
        {
            const float* ib = img + (v * 3) * HW_;
            #pragma unroll
            for (int t = 0; t < 4; ++t) {
                rv0 += wt[t] * ib[offp[t]];
                rv1 += wt[t] * ib[HW_ + offp[t]];
                rv2 += wt[t] * ib[2 * HW_ + offp[t]];
            }
        }
        rgbv0[v] = rv0; rgbv1[v] = rv1; rgbv2[v] = rv2;
        // source direction
        float sdx = cam[v*3+0]-px, sdy = cam[v*3+1]-py, sdz = cam[v*3+2]-pz;
        float snv = sqrtf(sdx*sdx + sdy*sdy + sdz*sdz);
        sdx /= snv; sdy /= snv; sdz /= snv;

        // x vector distributed across lanes 0..40
        float xl = 0.f;
        if (lane < 3) {
            xl = (lane == 0) ? rv0 : ((lane == 1) ? rv1 : rv2);
        } else if (lane < 35) {
            if (PACKED) {
                const float* fb = pk + (size_t)v * HW_ * 32 + (lane - 3);
                xl = wt[0]*fb[offp[0]*32] + wt[1]*fb[offp[1]*32]
                   + wt[2]*fb[offp[2]*32] + wt[3]*fb[offp[3]*32];
            } else {
                const float* fb = fea + (size_t)(v * (2*L_) + FS + (lane - 3)) * HW_;
                xl = wt[0]*fb[offp[0]] + wt[1]*fb[offp[1]]
                   + wt[2]*fb[offp[2]] + wt[3]*fb[offp[3]];
            }
        } else if (lane == 35) xl = sdx;
        else if (lane == 36) xl = sdy;
        else if (lane == 37) xl = sdz;
        else if (lane == 38) xl = rdx;
        else if (lane == 39) xl = rdy;
        else if (lane == 40) xl = rdz;

        // h1 = relu(x @ W1 + b1)   (lane j computes channel j) — 4-way ILP
        float p0 = 0.f, p1 = 0.f, p2 = 0.f, p3 = 0.f;
        #pragma unroll
        for (int k = 0; k < 40; k += 4) {
            p0 += __shfl(xl, k+0, 64) * w1c[k+0];
            p1 += __shfl(xl, k+1, 64) * w1c[k+1];
            p2 += __shfl(xl, k+2, 64) * w1c[k+2];
            p3 += __shfl(xl, k+3, 64) * w1c[k+3];
        }
        p0 += __shfl(xl, 40, 64) * w1c[40];
        float h1 = fmaxf(b1j + ((p0 + p1) + (p2 + p3)), 0.f);

        // h = relu(h1 @ W2 + b2)
        float q0_ = 0.f, q1_ = 0.f, q2_ = 0.f, q3_ = 0.f;
        #pragma unroll
        for (int k = 0; k < HID_; k += 4) {
            q0_ += __shfl(h1, k+0, 64) * w2c[k+0];
            q1_ += __shfl(h1, k+1, 64) * w2c[k+1];
            q2_ += __shfl(h1, k+2, 64) * w2c[k+2];
            q3_ += __shfl(h1, k+3, 64) * w2c[k+3];
        }
        float h = fmaxf(b2j + ((q0_ + q1_) + (q2_ + q3_)), 0.f);

        sumh += h; sumq += h * h;
        // blend logit = h . Wb + bb  (wave allreduce)
        float tl = h * wbj;
        #pragma unroll
        for (int off = 32; off >= 1; off >>= 1) tl += __shfl_xor(tl, off, 64);
        logit[v] = tl + bbv;
    }

    // pooled -> density
    float mean = sumh * (1.0f / V_);
    float var  = sumq * (1.0f / V_) - mean * mean;
    float dt = mean * wd0 + var * wd1;
    #pragma unroll
    for (int off = 32; off >= 1; off >>= 1) dt += __shfl_xor(dt, off, 64);
    float density = dt + bdv;

    // softmax blend over views -> rgb
    float mx = logit[0];
    #pragma unroll
    for (int v = 1; v < V_; ++v) mx = fmaxf(mx, logit[v]);
    float es = 0.f, a0 = 0.f, a1c = 0.f, a2c = 0.f;
    #pragma unroll
    for (int v = 0; v < V_; ++v) {
        float e = expf(logit[v] - mx);
        es += e;
        a0 += e * rgbv0[v]; a1c += e * rgbv1[v]; a2c += e * rgbv2[v];
    }
    bool hull = hullsum > ((float)V_ - 0.001f);
    if (lane == 0) {
        float is = 1.0f / es;
        odens[wid]      = hull ? density   : 0.f;
        orgb[wid*3 + 0] = hull ? a0  * is  : 0.f;
        orgb[wid*3 + 1] = hull ? a1c * is  : 0.f;
        orgb[wid*3 + 2] = hull ? a2c * is  : 0.f;
    }
}

// ---------------------------------------- coarse composite + sample_pdf + merge
__global__ void k_comp_coarse(const float* __restrict__ ray,
                              const float* __restrict__ dens,
                              const float* __restrict__ rgb,
                              float* __restrict__ out,
                              float* __restrict__ fulld) {
    int r = blockIdx.x * blockDim.x + threadIdx.x;
    if (r >= R_) return;
    const float nv = ray[r*8+6], fv = ray[r*8+7];

    float wv[NC_];
    float T = 1.f, c0 = 0.f, c1 = 0.f, c2 = 0.f, cd = 0.f, ca = 0.f;
    for (int s = 0; s < NC_; ++s) {
        float d0 = nv + (fv - nv) * ((s + 0.5f) / NC_);
        float d1 = nv + (fv - nv) * ((s + 1.5f) / NC_);
        float delta = (s == NC_-1) ? 1e10f : (d1 - d0);
        float a = 1.f - expf(-fmaxf(dens[r*NC_+s], 0.f) * delta);
        float wi = a * T;
        wv[s] = wi;
        c0 += wi * rgb[(r*NC_+s)*3+0];
        c1 += wi * rgb[(r*NC_+s)*3+1];
        c2 += wi * rgb[(r*NC_+s)*3+2];
        cd += wi * d0; ca += wi;
        T *= (1.f - a + 1e-10f);
    }
    out[r*3+0] = c0; out[r*3+1] = c1; out[r*3+2] = c2;
    out[3072 + r] = cd;
    out[4096 + r] = ca;

    // ---- sample_pdf(mids, w[1:-1], NF) ----
    float tot = 0.f;
    for (int i = 0; i < 62; ++i) tot += wv[i+1] + 1e-5f;
    float cdf[63];
    cdf[0] = 0.f;
    float run = 0.f;
    for (int i = 0; i < 62; ++i) { run += (wv[i+1] + 1e-5f) / tot; cdf[i+1] = run; }

    float fd[NF_];
    int idx = 1;                      // searchsorted(cdf, u, 'right'), u>0 so >=1
    for (int i = 0; i < NF_; ++i) {
        float u = (i + 0.5f) / NF_;
        while (idx < 63 && cdf[idx] <= u) ++idx;
        int below = idx - 1;
        int above = (idx > 62) ? 62 : idx;
        float cA = cdf[below], cB = cdf[above];
        float b0 = nv + (fv - nv) * ((below + 1.0f) / NC_);
        float b1 = nv + (fv - nv) * ((above + 1.0f) / NC_);
        float dnm = cB - cA;
        dnm = (dnm < 1e-5f) ? 1.f : dnm;
        float t = (u - cA) / dnm;
        fd[i] = b0 + t * (b1 - b0);
    }
    // ---- merge coarse (formula, sorted) with fd (sorted) -> full_depth ----
    float* fl = fulld + r * (NC_ + NF_);
    int a_ = 0, b_ = 0;
    for (int i = 0; i < NC_ + NF_; ++i) {
        float da = (a_ < NC_) ? nv + (fv - nv) * ((a_ + 0.5f) / NC_) : 3.0e38f;
        float db = (b_ < NF_) ? fd[b_] : 3.0e38f;
        if (da <= db) { fl[i] = da; ++a_; } else { fl[i] = db; ++b_; }
    }
}

// ---------------------------------------------------------- fine composite
__global__ void k_comp_fine(const float* __restrict__ fulld,
                            const float* __restrict__ dens,
                            const float* __restrict__ rgb,
                            float* __restrict__ out) {
    int r = blockIdx.x * blockDim.x + threadIdx.x;
    if (r >= R_) return;
    const int S = NC_ + NF_;
    const float* fl = fulld + r * S;
    float T = 1.f, c0 = 0.f, c1 = 0.f, c2 = 0.f, cd = 0.f, ca = 0.f;
    for (int s = 0; s < S; ++s) {
        float d0 = fl[s];
        float delta = (s == S-1) ? 1e10f : (fl[s+1] - d0);
        float a = 1.f - expf(-fmaxf(dens[r*S+s], 0.f) * delta);
        float wi = a * T;
        c0 += wi * rgb[(r*S+s)*3+0];
        c1 += wi * rgb[(r*S+s)*3+1];
        c2 += wi * rgb[(r*S+s)*3+2];
        cd += wi * d0; ca += wi;
        T *= (1.f - a + 1e-10f);
    }
    out[5120 + r*3+0] = c0; out[5120 + r*3+1] = c1; out[5120 + r*3+2] = c2;
    out[8192 + r] = cd;
    out[9216 + r] = ca;
}

// ------------------------------------------------------------------ launch
extern "C" void kernel_launch(void* const* d_in, const int* in_sizes, int n_in,
                              void* d_out, int out_size, void* d_ws, size_t ws_size,
                              hipStream_t stream) {
    const float* ray = (const float*)d_in[0];
    const float* Kin = (const float*)d_in[1];
    const float* Ein = (const float*)d_in[2];
    const float* cam = (const float*)d_in[3];
    const float* shp = (const float*)d_in[4];
    const float* msk = (const float*)d_in[5];
    const float* img = (const float*)d_in[6];
    const float* fea = (const float*)d_in[7];
    const float* cw[8]; for (int i = 0; i < 8; ++i) cw[i] = (const float*)d_in[8+i];
    const float* fw[8]; for (int i = 0; i < 8; ++i) fw[i] = (const float*)d_in[16+i];

    float* ws    = (float*)d_ws;
    float* Pm    = ws;                       // 96
    float* WT    = Pm + 96;                  // 13824 (cW1T 2816 | cW2T 4096 | fW1T 2816 | fW2T 4096)
    float* cdens = WT + 13824;               // R*NC
    float* crgb  = cdens + R_ * NC_;         // R*NC*3
    float* fulld = crgb + R_ * NC_ * 3;      // R*128
    float* fdens = fulld + R_ * (NC_+NF_);   // R*128
    float* frgb  = fdens + R_ * (NC_+NF_);   // R*128*3
    float* pk    = frgb + R_ * (NC_+NF_) * 3;// V*HW*32 = 16,777,216 floats (67 MB)

    size_t base_floats = (size_t)(pk - ws);
    size_t need_bytes  = (base_floats + (size_t)V_ * HW_ * 32 + 64) * sizeof(float);
    bool packed = (ws_size >= need_bytes);

    float* outp  = (float*)d_out;

    k_computeP<<<1, 96, 0, stream>>>(Kin, Ein, Pm);

    if (packed) {
        k_packW<<<16, 256, 0, stream>>>(cw[0], cw[2], fw[0], fw[2], WT);
        k_packF<<<dim3(W_/64, H_, V_), 256, 0, stream>>>(fea, pk, 0);

        k_points<NC_, 0, false, true><<<R_ * NC_ / 4, 256, 0, stream>>>(
            ray, Pm, cam, shp, msk, img, fea, pk, WT, WT + 2816,
            cw[0], cw[1], cw[2], cw[3], cw[4], cw[5], cw[6], cw[7],
            nullptr, cdens, crgb);

        k_comp_coarse<<<R_ / 256, 256, 0, stream>>>(ray, cdens, crgb, outp, fulld);

        k_packF<<<dim3(W_/64, H_, V_), 256, 0, stream>>>(fea, pk, L_);

        k_points<NC_ + NF_, L_, true, true><<<R_ * (NC_+NF_) / 4, 256, 0, stream>>>(
            ray, Pm, cam, shp, msk, img, fea, pk, WT + 6912, WT + 9728,
            fw[0], fw[1], fw[2], fw[3], fw[4], fw[5], fw[6], fw[7],
            fulld, fdens, frgb);

        k_comp_fine<<<R_ / 256, 256, 0, stream>>>(fulld, fdens, frgb, outp);
    } else {
        k_points<NC_, 0, false, false><<<R_ * NC_ / 4, 256, 0, stream>>>(
            ray, Pm, cam, shp, msk, img, fea, nullptr, nullptr, nullptr,
            cw[0], cw[1], cw[2], cw[3], cw[4], cw[5], cw[6], cw[7],
            nullptr, cdens, crgb);

        k_comp_coarse<<<R_ / 256, 256, 0, stream>>>(ray, cdens, crgb, outp, fulld);

        k_points<NC_ + NF_, L_, true, false><<<R_ * (NC_+NF_) / 4, 256, 0, stream>>>(
            ray, Pm, cam, shp, msk, img, fea, nullptr, nullptr, nullptr,
            fw[0], fw[1], fw[2], fw[3], fw[4], fw[5], fw[6], fw[7],
            fulld, fdens, frgb);

        k_comp_fine<<<R_ / 256, 256, 0, stream>>>(fulld, fdens, frgb, outp);
    }
}

// Round 3
// 1025.010 us; speedup vs baseline: 6.0182x; 6.0182x over previous
//
#include <hip/hip_runtime.h>
#include <math.h>

#define V_   8
#define H_   256
#define W_   256
#define L_   32
#define HID_ 64
#define NC_  64
#define NF_  64
#define R_   1024
#define IND_ 41              // 3 + 32 + 3 + 3
#define HW_  (H_*W_)

// ---------------------------------------------------------------- P = K @ E
__global__ void k_computeP(const float* __restrict__ Km,
                           const float* __restrict__ Em,
                           float* __restrict__ Pm) {
    int t = threadIdx.x;
    if (t >= V_ * 12) return;
    int v = t / 12, e = t - v * 12, row = e >> 2, col = e & 3;
    float acc = 0.f;
    #pragma unroll
    for (int k = 0; k < 3; ++k)
        acc += Km[v * 9 + row * 3 + k] * Em[v * 12 + k * 4 + col];
    Pm[v * 12 + row * 4 + col] = acc;
}

// ------------------------------------------- transpose weights, contiguous rows
// layout: [cW1T 64x48 @0][cW2T 64x64 @3072][fW1T @7168][fW2T @10240]  (14336 fl)
__global__ void k_packW(const float* __restrict__ W1c, const float* __restrict__ W2c,
                        const float* __restrict__ W1f, const float* __restrict__ W2f,
                        float* __restrict__ out) {
    int t = threadIdx.x + blockIdx.x * blockDim.x;
    if (t < 64 * 48) {                      // zero-pad W1T rows (48 per row)
        int j = t / 48, k = t - j * 48;
        float a = (k < IND_) ? W1c[k * 64 + j] : 0.f;
        float b = (k < IND_) ? W1f[k * 64 + j] : 0.f;
        out[j * 48 + k]        = a;
        out[7168 + j * 48 + k] = b;
    }
    if (t < 64 * 64) {
        int j = t >> 6, k = t & 63;
        out[3072  + j * 64 + k] = W2c[k * 64 + j];
        out[10240 + j * 64 + k] = W2f[k * 64 + j];
    }
}

// -------------------------- pack 32 feature channels to pixel-major [V][HW][32]
__global__ __launch_bounds__(256) void k_packF(const float* __restrict__ fea,
                                               float* __restrict__ pk, int FS) {
    __shared__ float tile[32][65];
    const int xb = blockIdx.x * 64, y = blockIdx.y, v = blockIdx.z;
    const int t = threadIdx.x;
    #pragma unroll
    for (int step = 0; step < 8; ++step) {
        int c = step * 4 + (t >> 6);
        int x = t & 63;
        tile[c][x] = fea[((size_t)(v * 2 * L_ + FS + c)) * HW_ + y * W_ + xb + x];
    }
    __syncthreads();
    #pragma unroll
    for (int step = 0; step < 8; ++step) {
        int x = step * 8 + (t >> 5);
        int c = t & 31;
        pk[((size_t)v * HW_ + y * W_ + xb + x) * 32 + c] = tile[c][x];
    }
}

// ------------------------------------------------------------- MLP kernel
// lane = (point, view): 8 points x 8 views per wave. Weights are wave-uniform
// -> scalar operands. View pooling via __shfl_xor over lane bits 0..2.
template <int S, int FS, bool FINE, bool PACKED>
__global__ __launch_bounds__(256, 2) void k_mlp(
    const float* __restrict__ ray, const float* __restrict__ Pm,
    const float* __restrict__ cam, const float* __restrict__ shp,
    const float* __restrict__ msk, const float* __restrict__ img,
    const float* __restrict__ fea, const float* __restrict__ pk,
    const float* __restrict__ WT1, const float* __restrict__ WT2,
    const float* __restrict__ W1, const float* __restrict__ b1,
    const float* __restrict__ W2, const float* __restrict__ b2,
    const float* __restrict__ Wd, const float* __restrict__ bd,
    const float* __restrict__ Wb, const float* __restrict__ bb,
    const float* __restrict__ deptharr,
    float* __restrict__ odens, float* __restrict__ orgb) {

    const int tid = blockIdx.x * 256 + threadIdx.x;
    const int v   = tid & 7;            // view for this lane
    const int P   = tid >> 3;           // point-sample id
    const int r   = P / S, s = P - r * S;

    const float ox = ray[r*8+0], oy = ray[r*8+1], oz = ray[r*8+2];
    const float dx = ray[r*8+3], dy = ray[r*8+4], dz = ray[r*8+5];
    const float nv = ray[r*8+6], fv = ray[r*8+7];

    float depth;
    if (FINE) depth = deptharr[P];
    else      depth = nv + (fv - nv) * ((s + 0.5f) / (float)S);

    const float px = ox + dx*depth, py = oy + dy*depth, pz = oz + dz*depth;
    const float dn = sqrtf(dx*dx + dy*dy + dz*dz);
    const float rdx = -dx/dn, rdy = -dy/dn, rdz = -dz/dn;

    // ---- projection for this lane's view ----
    const float* Pv = Pm + v * 12;
    float q0 = Pv[0]*px + Pv[1]*py + Pv[2]*pz  + Pv[3];
    float q1 = Pv[4]*px + Pv[5]*py + Pv[6]*pz  + Pv[7];
    float q2 = Pv[8]*px + Pv[9]*py + Pv[10]*pz + Pv[11];
    float inv = 1.0f / (q2 + 1e-6f);
    float u = q0 * inv, w = q1 * inv;
    float gx = 2.0f * (u / shp[v*2+1]) - 1.0f;
    float gy = 2.0f * (w / shp[v*2+0]) - 1.0f;
    float sx = (gx + 1.0f) * ((float)W_ * 0.5f) - 0.5f;
    float sy = (gy + 1.0f) * ((float)H_ * 0.5f) - 0.5f;
    float x0f = floorf(sx), y0f = floorf(sy);
    float fx = sx - x0f, fy = sy - y0f;

    int offp[4]; float wt[4];
    {
        float xs[2] = {x0f, x0f + 1.f}, ys[2] = {y0f, y0f + 1.f};
        float wxs[2] = {1.f - fx, fx},  wys[2] = {1.f - fy, fy};
        #pragma unroll
        for (int t = 0; t < 4; ++t) {
            float xf = xs[t & 1], yf = ys[t >> 1];
            bool val = (xf >= 0.f) && (xf <= (float)(W_-1)) &&
                       (yf >= 0.f) && (yf <= (float)(H_-1));
            int xi = (int)fminf(fmaxf(xf, 0.f), (float)(W_-1));
            int yi = (int)fminf(fmaxf(yf, 0.f), (float)(H_-1));
            offp[t] = yi * W_ + xi;
            wt[t] = wxs[t & 1] * wys[t >> 1] * (val ? 1.f : 0.f);
        }
    }

    // mask sample
    const float* mb = msk + v * HW_;
    float msample = wt[0]*mb[offp[0]] + wt[1]*mb[offp[1]]
                  + wt[2]*mb[offp[2]] + wt[3]*mb[offp[3]];
    // rgb sample
    float rv0 = 0.f, rv1 = 0.f, rv2 = 0.f;
    {
        const float* ib = img + (v * 3) * HW_;
        #pragma unroll
        for (int t = 0; t < 4; ++t) {
            rv0 += wt[t] * ib[offp[t]];
            rv1 += wt[t] * ib[HW_ + offp[t]];
            rv2 += wt[t] * ib[2 * HW_ + offp[t]];
        }
    }
    // source dir
    float sdx = cam[v*3+0]-px, sdy = cam[v*3+1]-py, sdz = cam[v*3+2]-pz;
    float snv = sqrtf(sdx*sdx + sdy*sdy + sdz*sdz);
    sdx /= snv; sdy /= snv; sdz /= snv;

    // ---- build x[41] (lane-local) ----
    float x[IND_];
    x[0] = rv0; x[1] = rv1; x[2] = rv2;
    #pragma unroll
    for (int i = 3; i < 35; ++i) x[i] = 0.f;
    if (PACKED) {
        #pragma unroll
        for (int t = 0; t < 4; ++t) {
            const float4* fp = (const float4*)(pk + ((size_t)v * HW_ + offp[t]) * 32);
            float wtt = wt[t];
            #pragma unroll
            for (int k4 = 0; k4 < 8; ++k4) {
                float4 f = fp[k4];
                x[3+k4*4+0] += wtt * f.x;
                x[3+k4*4+1] += wtt * f.y;
                x[3+k4*4+2] += wtt * f.z;
                x[3+k4*4+3] += wtt * f.w;
            }
        }
    } else {
        #pragma unroll
        for (int k = 0; k < 32; ++k) {
            const float* fb = fea + (size_t)(v * (2*L_) + FS + k) * HW_;
            x[3+k] = wt[0]*fb[offp[0]] + wt[1]*fb[offp[1]]
                   + wt[2]*fb[offp[2]] + wt[3]*fb[offp[3]];
        }
    }
    x[35] = sdx; x[36] = sdy; x[37] = sdz;
    x[38] = rdx; x[39] = rdy; x[40] = rdz;

    // ---- layer 1: h1 = relu(x @ W1 + b1); weights scalar (wave-uniform) ----
    float h1[HID_];
    #pragma unroll
    for (int j = 0; j < HID_; ++j) {
        float a = b1[j];
        if (PACKED) {
            const float* wr = WT1 + j * 48;
            #pragma unroll
            for (int k = 0; k < IND_; ++k) a += x[k] * wr[k];
        } else {
            #pragma unroll
            for (int k = 0; k < IND_; ++k) a += x[k] * W1[k * HID_ + j];
        }
        h1[j] = fmaxf(a, 0.f);
    }

    // ---- layer 2 fused with pooling (h never stored) ----
    float dacc = 0.f;
    float lg = bb[0];
    #pragma unroll
    for (int j = 0; j < HID_; ++j) {
        float a = b2[j];
        if (PACKED) {
            const float* wr = WT2 + j * 64;
            #pragma unroll
            for (int k = 0; k < HID_; ++k) a += h1[k] * wr[k];
        } else {
            #pragma unroll
            for (int k = 0; k < HID_; ++k) a += h1[k] * W2[k * HID_ + j];
        }
        float h = fmaxf(a, 0.f);
        lg += h * Wb[j];
        // mean/var over the 8 view-lanes (lane bits 0..2)
        float sh = h;
        sh += __shfl_xor(sh, 1); sh += __shfl_xor(sh, 2); sh += __shfl_xor(sh, 4);
        float sq = h * h;
        sq += __shfl_xor(sq, 1); sq += __shfl_xor(sq, 2); sq += __shfl_xor(sq, 4);
        float mean = sh * 0.125f;
        float var  = sq * 0.125f - mean * mean;
        dacc += mean * Wd[j] + var * Wd[HID_ + j];
    }
    float density = dacc + bd[0];

    // hull: sum of mask samples over views
    float hs = msample;
    hs += __shfl_xor(hs, 1); hs += __shfl_xor(hs, 2); hs += __shfl_xor(hs, 4);
    bool hull = hs > ((float)V_ - 0.001f);

    // softmax blend over views
    float mx = lg;
    mx = fmaxf(mx, __shfl_xor(mx, 1));
    mx = fmaxf(mx, __shfl_xor(mx, 2));
    mx = fmaxf(mx, __shfl_xor(mx, 4));
    float e = expf(lg - mx);
    float es = e;
    es += __shfl_xor(es, 1); es += __shfl_xor(es, 2); es += __shfl_xor(es, 4);
    float br = e * rv0, bg = e * rv1, bbl = e * rv2;
    br  += __shfl_xor(br, 1);  br  += __shfl_xor(br, 2);  br  += __shfl_xor(br, 4);
    bg  += __shfl_xor(bg, 1);  bg  += __shfl_xor(bg, 2);  bg  += __shfl_xor(bg, 4);
    bbl += __shfl_xor(bbl, 1); bbl += __shfl_xor(bbl, 2); bbl += __shfl_xor(bbl, 4);

    if (v == 0) {
        float is = 1.0f / es;
        odens[P]      = hull ? density  : 0.f;
        orgb[P*3 + 0] = hull ? br  * is : 0.f;
        orgb[P*3 + 1] = hull ? bg  * is : 0.f;
        orgb[P*3 + 2] = hull ? bbl * is : 0.f;
    }
}

// ---------------------------------------- coarse composite + sample_pdf + merge
__global__ void k_comp_coarse(const float* __restrict__ ray,
                              const float* __restrict__ dens,
                              const float* __restrict__ rgb,
                              float* __restrict__ out,
                              float* __restrict__ fulld) {
    int r = blockIdx.x * blockDim.x + threadIdx.x;
    if (r >= R_) return;
    const float nv = ray[r*8+6], fv = ray[r*8+7];

    float wv[NC_];
    float T = 1.f, c0 = 0.f, c1 = 0.f, c2 = 0.f, cd = 0.f, ca = 0.f;
    for (int s = 0; s < NC_; ++s) {
        float d0 = nv + (fv - nv) * ((s + 0.5f) / NC_);
        float d1 = nv + (fv - nv) * ((s + 1.5f) / NC_);
        float delta = (s == NC_-1) ? 1e10f : (d1 - d0);
        float a = 1.f - expf(-fmaxf(dens[r*NC_+s], 0.f) * delta);
        float wi = a * T;
        wv[s] = wi;
        c0 += wi * rgb[(r*NC_+s)*3+0];
        c1 += wi * rgb[(r*NC_+s)*3+1];
        c2 += wi * rgb[(r*NC_+s)*3+2];
        cd += wi * d0; ca += wi;
        T *= (1.f - a + 1e-10f);
    }
    out[r*3+0] = c0; out[r*3+1] = c1; out[r*3+2] = c2;
    out[3072 + r] = cd;
    out[4096 + r] = ca;

    // ---- sample_pdf(mids, w[1:-1], NF) ----
    float tot = 0.f;
    for (int i = 0; i < 62; ++i) tot += wv[i+1] + 1e-5f;
    float cdf[63];
    cdf[0] = 0.f;
    float run = 0.f;
    for (int i = 0; i < 62; ++i) { run += (wv[i+1] + 1e-5f) / tot; cdf[i+1] = run; }

    float fd[NF_];
    int idx = 1;
    for (int i = 0; i < NF_; ++i) {
        float u = (i + 0.5f) / NF_;
        while (idx < 63 && cdf[idx] <= u) ++idx;
        int below = idx - 1;
        int above = (idx > 62) ? 62 : idx;
        float cA = cdf[below], cB = cdf[above];
        float b0 = nv + (fv - nv) * ((below + 1.0f) / NC_);
        float b1 = nv + (fv - nv) * ((above + 1.0f) / NC_);
        float dnm = cB - cA;
        dnm = (dnm < 1e-5f) ? 1.f : dnm;
        float t = (u - cA) / dnm;
        fd[i] = b0 + t * (b1 - b0);
    }
    float* fl = fulld + r * (NC_ + NF_);
    int a_ = 0, b_ = 0;
    for (int i = 0; i < NC_ + NF_; ++i) {
        float da = (a_ < NC_) ? nv + (fv - nv) * ((a_ + 0.5f) / NC_) : 3.0e38f;
        float db = (b_ < NF_) ? fd[b_] : 3.0e38f;
        if (da <= db) { fl[i] = da; ++a_; } else { fl[i] = db; ++b_; }
    }
}

// ---------------------------------------------------------- fine composite
__global__ void k_comp_fine(const float* __restrict__ fulld,
                            const float* __restrict__ dens,
                            const float* __restrict__ rgb,
                            float* __restrict__ out) {
    int r = blockIdx.x * blockDim.x + threadIdx.x;
    if (r >= R_) return;
    const int S = NC_ + NF_;
    const float* fl = fulld + r * S;
    float T = 1.f, c0 = 0.f, c1 = 0.f, c2 = 0.f, cd = 0.f, ca = 0.f;
    for (int s = 0; s < S; ++s) {
        float d0 = fl[s];
        float delta = (s == S-1) ? 1e10f : (fl[s+1] - d0);
        float a = 1.f - expf(-fmaxf(dens[r*S+s], 0.f) * delta);
        float wi = a * T;
        c0 += wi * rgb[(r*S+s)*3+0];
        c1 += wi * rgb[(r*S+s)*3+1];
        c2 += wi * rgb[(r*S+s)*3+2];
        cd += wi * d0; ca += wi;
        T *= (1.f - a + 1e-10f);
    }
    out[5120 + r*3+0] = c0; out[5120 + r*3+1] = c1; out[5120 + r*3+2] = c2;
    out[8192 + r] = cd;
    out[9216 + r] = ca;
}

// ------------------------------------------------------------------ launch
extern "C" void kernel_launch(void* const* d_in, const int* in_sizes, int n_in,
                              void* d_out, int out_size, void* d_ws, size_t ws_size,
                              hipStream_t stream) {
    const float* ray = (const float*)d_in[0];
    const float* Kin = (const float*)d_in[1];
    const float* Ein = (const float*)d_in[2];
    const float* cam = (const float*)d_in[3];
    const float* shp = (const float*)d_in[4];
    const float* msk = (const float*)d_in[5];
    const float* img = (const float*)d_in[6];
    const float* fea = (const float*)d_in[7];
    const float* cw[8]; for (int i = 0; i < 8; ++i) cw[i] = (const float*)d_in[8+i];
    const float* fw[8]; for (int i = 0; i < 8; ++i) fw[i] = (const float*)d_in[16+i];

    float* ws    = (float*)d_ws;
    float* Pm    = ws;                       // 96
    float* WT    = Pm + 96;                  // 14336
    float* cdens = WT + 14336;               // R*NC            = 65536
    float* crgb  = cdens + R_ * NC_;         // R*NC*3          = 196608
    float* fulld = crgb + R_ * NC_ * 3;      // R*128           = 131072
    float* fdens = fulld + R_ * (NC_+NF_);   // R*128           = 131072
    float* frgb  = fdens + R_ * (NC_+NF_);   // R*128*3         = 393216
    float* pk    = frgb + R_ * (NC_+NF_) * 3;// V*HW*32         = 16777216

    size_t base_floats = (size_t)(pk - ws);
    size_t need_bytes  = (base_floats + (size_t)V_ * HW_ * 32 + 64) * sizeof(float);
    bool packed = (ws_size >= need_bytes);

    float* outp  = (float*)d_out;

    k_computeP<<<1, 96, 0, stream>>>(Kin, Ein, Pm);

    if (packed) {
        k_packW<<<16, 256, 0, stream>>>(cw[0], cw[2], fw[0], fw[2], WT);
        k_packF<<<dim3(W_/64, H_, V_), 256, 0, stream>>>(fea, pk, 0);

        k_mlp<NC_, 0, false, true><<<R_ * NC_ * 8 / 256, 256, 0, stream>>>(
            ray, Pm, cam, shp, msk, img, fea, pk, WT, WT + 3072,
            cw[0], cw[1], cw[2], cw[3], cw[4], cw[5], cw[6], cw[7],
            nullptr, cdens, crgb);

        k_comp_coarse<<<R_ / 256, 256, 0, stream>>>(ray, cdens, crgb, outp, fulld);

        k_packF<<<dim3(W_/64, H_, V_), 256, 0, stream>>>(fea, pk, L_);

        k_mlp<NC_ + NF_, L_, true, true><<<R_ * (NC_+NF_) * 8 / 256, 256, 0, stream>>>(
            ray, Pm, cam, shp, msk, img, fea, pk, WT + 7168, WT + 10240,
            fw[0], fw[1], fw[2], fw[3], fw[4], fw[5], fw[6], fw[7],
            fulld, fdens, frgb);

        k_comp_fine<<<R_ / 256, 256, 0, stream>>>(fulld, fdens, frgb, outp);
    } else {
        k_mlp<NC_, 0, false, false><<<R_ * NC_ * 8 / 256, 256, 0, stream>>>(
            ray, Pm, cam, shp, msk, img, fea, nullptr, nullptr, nullptr,
            cw[0], cw[1], cw[2], cw[3], cw[4], cw[5], cw[6], cw[7],
            nullptr, cdens, crgb);

        k_comp_coarse<<<R_ / 256, 256, 0, stream>>>(ray, cdens, crgb, outp, fulld);

        k_mlp<NC_ + NF_, L_, true, false><<<R_ * (NC_+NF_) * 8 / 256, 256, 0, stream>>>(
            ray, Pm, cam, shp, msk, img, fea, nullptr, nullptr, nullptr,
            fw[0], fw[1], fw[2], fw[3], fw[4], fw[5], fw[6], fw[7],
            fulld, fdens, frgb);

        k_comp_fine<<<R_ / 256, 256, 0, stream>>>(fulld, fdens, frgb, outp);
    }
}

// Round 4
// 647.036 us; speedup vs baseline: 9.5338x; 1.5842x over previous
//
#include <hip/hip_runtime.h>
#include <math.h>

#define V_   8
#define H_   256
#define W_   256
#define L_   32
#define HID_ 64
#define NC_  64
#define NF_  64
#define R_   1024
#define IND_ 41              // 3 + 32 + 3 + 3
#define HW_  (H_*W_)

// ---------------------------------------------------------------- P = K @ E
__global__ void k_computeP(const float* __restrict__ Km,
                           const float* __restrict__ Em,
                           float* __restrict__ Pm) {
    int t = threadIdx.x;
    if (t >= V_ * 12) return;
    int v = t / 12, e = t - v * 12, row = e >> 2, col = e & 3;
    float acc = 0.f;
    #pragma unroll
    for (int k = 0; k < 3; ++k)
        acc += Km[v * 9 + row * 3 + k] * Em[v * 12 + k * 4 + col];
    Pm[v * 12 + row * 4 + col] = acc;
}

// ------------------------------------------- transpose weights, contiguous rows
// layout: [cW1T 64x48 @0][cW2T 64x64 @3072][fW1T @7168][fW2T @10240]  (14336 fl)
__global__ void k_packW(const float* __restrict__ W1c, const float* __restrict__ W2c,
                        const float* __restrict__ W1f, const float* __restrict__ W2f,
                        float* __restrict__ out) {
    int t = threadIdx.x + blockIdx.x * blockDim.x;
    if (t < 64 * 48) {                      // zero-pad W1T rows (48 per row)
        int j = t / 48, k = t - j * 48;
        float a = (k < IND_) ? W1c[k * 64 + j] : 0.f;
        float b = (k < IND_) ? W1f[k * 64 + j] : 0.f;
        out[j * 48 + k]        = a;
        out[7168 + j * 48 + k] = b;
    }
    if (t < 64 * 64) {
        int j = t >> 6, k = t & 63;
        out[3072  + j * 64 + k] = W2c[k * 64 + j];
        out[10240 + j * 64 + k] = W2f[k * 64 + j];
    }
}

// -------------------------- pack 32 feature channels to pixel-major [V][HW][32]
__global__ __launch_bounds__(256) void k_packF(const float* __restrict__ fea,
                                               float* __restrict__ pk, int FS) {
    __shared__ float tile[32][65];
    const int xb = blockIdx.x * 64, y = blockIdx.y, v = blockIdx.z;
    const int t = threadIdx.x;
    #pragma unroll
    for (int step = 0; step < 8; ++step) {
        int c = step * 4 + (t >> 6);
        int x = t & 63;
        tile[c][x] = fea[((size_t)(v * 2 * L_ + FS + c)) * HW_ + y * W_ + xb + x];
    }
    __syncthreads();
    #pragma unroll
    for (int step = 0; step < 8; ++step) {
        int x = step * 8 + (t >> 5);
        int c = t & 31;
        pk[((size_t)v * HW_ + y * W_ + xb + x) * 32 + c] = tile[c][x];
    }
}

// ------------------------------------------------------------- MLP kernel
// lane = (point, view): 8 points x 8 views per wave. Weights wave-uniform
// (scalar operands). Layer1 fully unrolled (static x[], h1[] indices ->
// registers); layer2 is a runtime j-loop (code stays < L1I). Pooling:
// per-lane A/B accumulators reduced once at the end; only mean^2 needs a
// per-j 3-shuffle view-sum.
template <int S, int FS, bool FINE, bool PACKED>
__global__ __launch_bounds__(256, 2) void k_mlp(
    const float* __restrict__ ray, const float* __restrict__ Pm,
    const float* __restrict__ cam, const float* __restrict__ shp,
    const float* __restrict__ msk, const float* __restrict__ img,
    const float* __restrict__ fea, const float* __restrict__ pk,
    const float* __restrict__ WT1, const float* __restrict__ WT2,
    const float* __restrict__ W1, const float* __restrict__ b1,
    const float* __restrict__ W2, const float* __restrict__ b2,
    const float* __restrict__ Wd, const float* __restrict__ bd,
    const float* __restrict__ Wb, const float* __restrict__ bb,
    const float* __restrict__ deptharr,
    float* __restrict__ odens, float* __restrict__ orgb) {

    const int tid = blockIdx.x * 256 + threadIdx.x;
    const int v   = tid & 7;            // view for this lane
    const int P   = tid >> 3;           // point-sample id
    const int r   = P / S, s = P - r * S;

    const float ox = ray[r*8+0], oy = ray[r*8+1], oz = ray[r*8+2];
    const float dx = ray[r*8+3], dy = ray[r*8+4], dz = ray[r*8+5];
    const float nv = ray[r*8+6], fv = ray[r*8+7];

    float depth;
    if (FINE) depth = deptharr[P];
    else      depth = nv + (fv - nv) * ((s + 0.5f) / (float)S);

    const float px = ox + dx*depth, py = oy + dy*depth, pz = oz + dz*depth;
    const float dn = sqrtf(dx*dx + dy*dy + dz*dz);
    const float rdx = -dx/dn, rdy = -dy/dn, rdz = -dz/dn;

    // ---- projection for this lane's view ----
    const float* Pv = Pm + v * 12;
    float q0 = Pv[0]*px + Pv[1]*py + Pv[2]*pz  + Pv[3];
    float q1 = Pv[4]*px + Pv[5]*py + Pv[6]*pz  + Pv[7];
    float q2 = Pv[8]*px + Pv[9]*py + Pv[10]*pz + Pv[11];
    float inv = 1.0f / (q2 + 1e-6f);
    float u = q0 * inv, w = q1 * inv;
    float gx = 2.0f * (u / shp[v*2+1]) - 1.0f;
    float gy = 2.0f * (w / shp[v*2+0]) - 1.0f;
    float sx = (gx + 1.0f) * ((float)W_ * 0.5f) - 0.5f;
    float sy = (gy + 1.0f) * ((float)H_ * 0.5f) - 0.5f;
    float x0f = floorf(sx), y0f = floorf(sy);
    float fx = sx - x0f, fy = sy - y0f;

    int offp[4]; float wt[4];
    {
        float xs[2] = {x0f, x0f + 1.f}, ys[2] = {y0f, y0f + 1.f};
        float wxs[2] = {1.f - fx, fx},  wys[2] = {1.f - fy, fy};
        #pragma unroll
        for (int t = 0; t < 4; ++t) {
            float xf = xs[t & 1], yf = ys[t >> 1];
            bool val = (xf >= 0.f) && (xf <= (float)(W_-1)) &&
                       (yf >= 0.f) && (yf <= (float)(H_-1));
            int xi = (int)fminf(fmaxf(xf, 0.f), (float)(W_-1));
            int yi = (int)fminf(fmaxf(yf, 0.f), (float)(H_-1));
            offp[t] = yi * W_ + xi;
            wt[t] = wxs[t & 1] * wys[t >> 1] * (val ? 1.f : 0.f);
        }
    }

    // mask sample
    const float* mb = msk + v * HW_;
    float msample = wt[0]*mb[offp[0]] + wt[1]*mb[offp[1]]
                  + wt[2]*mb[offp[2]] + wt[3]*mb[offp[3]];
    // rgb sample
    float rv0 = 0.f, rv1 = 0.f, rv2 = 0.f;
    {
        const float* ib = img + (v * 3) * HW_;
        #pragma unroll
        for (int t = 0; t < 4; ++t) {
            rv0 += wt[t] * ib[offp[t]];
            rv1 += wt[t] * ib[HW_ + offp[t]];
            rv2 += wt[t] * ib[2 * HW_ + offp[t]];
        }
    }
    // source dir
    float sdx = cam[v*3+0]-px, sdy = cam[v*3+1]-py, sdz = cam[v*3+2]-pz;
    float snv = sqrtf(sdx*sdx + sdy*sdy + sdz*sdz);
    sdx /= snv; sdy /= snv; sdz /= snv;

    // ---- build x[41] (lane-local, statically indexed) ----
    float x[IND_];
    x[0] = rv0; x[1] = rv1; x[2] = rv2;
    #pragma unroll
    for (int i = 3; i < 35; ++i) x[i] = 0.f;
    if (PACKED) {
        #pragma unroll
        for (int t = 0; t < 4; ++t) {
            const float4* fp = (const float4*)(pk + ((size_t)v * HW_ + offp[t]) * 32);
            float wtt = wt[t];
            #pragma unroll
            for (int k4 = 0; k4 < 8; ++k4) {
                float4 f = fp[k4];
                x[3+k4*4+0] += wtt * f.x;
                x[3+k4*4+1] += wtt * f.y;
                x[3+k4*4+2] += wtt * f.z;
                x[3+k4*4+3] += wtt * f.w;
            }
        }
    } else {
        #pragma unroll
        for (int k = 0; k < 32; ++k) {
            const float* fb = fea + (size_t)(v * (2*L_) + FS + k) * HW_;
            x[3+k] = wt[0]*fb[offp[0]] + wt[1]*fb[offp[1]]
                   + wt[2]*fb[offp[2]] + wt[3]*fb[offp[3]];
        }
    }
    x[35] = sdx; x[36] = sdy; x[37] = sdz;
    x[38] = rdx; x[39] = rdy; x[40] = rdz;

    // ---- layer 1 (fully unrolled; static x/h1 indices) ----
    float h1[HID_];
    #pragma unroll
    for (int j = 0; j < HID_; ++j) {
        float a0 = 0.f, a1 = 0.f, a2 = 0.f, a3 = 0.f;
        if (PACKED) {
            const float* wr = WT1 + j * 48;
            #pragma unroll
            for (int k = 0; k < 40; k += 4) {
                a0 += x[k+0] * wr[k+0];
                a1 += x[k+1] * wr[k+1];
                a2 += x[k+2] * wr[k+2];
                a3 += x[k+3] * wr[k+3];
            }
            a0 += x[40] * wr[40];
        } else {
            #pragma unroll
            for (int k = 0; k < IND_; ++k) a0 += x[k] * W1[k * HID_ + j];
        }
        h1[j] = fmaxf(b1[j] + ((a0 + a1) + (a2 + a3)), 0.f);
    }

    // ---- layer 2 + pooling: runtime j-loop, 4 rows/iter ----
    float lg = bb[0];
    float A = 0.f, B = 0.f, C = 0.f;
    #pragma unroll 1
    for (int j = 0; j < HID_; j += 4) {
        float hh0, hh1, hh2, hh3;
        #pragma unroll
        for (int jj = 0; jj < 4; ++jj) {
            float a0 = 0.f, a1 = 0.f, a2 = 0.f, a3 = 0.f;
            if (PACKED) {
                const float* wr = WT2 + (j + jj) * 64;
                #pragma unroll
                for (int k = 0; k < HID_; k += 4) {
                    a0 += h1[k+0] * wr[k+0];
                    a1 += h1[k+1] * wr[k+1];
                    a2 += h1[k+2] * wr[k+2];
                    a3 += h1[k+3] * wr[k+3];
                }
            } else {
                #pragma unroll
                for (int k = 0; k < HID_; ++k) a0 += h1[k] * W2[k * HID_ + (j + jj)];
            }
            float hcur = fmaxf(b2[j + jj] + ((a0 + a1) + (a2 + a3)), 0.f);
            if (jj == 0) hh0 = hcur; else if (jj == 1) hh1 = hcur;
            else if (jj == 2) hh2 = hcur; else hh3 = hcur;
        }
        #pragma unroll
        for (int jj = 0; jj < 4; ++jj) {
            float h = (jj == 0) ? hh0 : (jj == 1) ? hh1 : (jj == 2) ? hh2 : hh3;
            lg += h * Wb[j + jj];
            A  += h * Wd[j + jj];
            B  += h * h * Wd[HID_ + j + jj];
            float sj = h;
            sj += __shfl_xor(sj, 1); sj += __shfl_xor(sj, 2); sj += __shfl_xor(sj, 4);
            C  += sj * sj * Wd[HID_ + j + jj];
        }
    }
    // reduce A, B over the 8 view-lanes
    A += __shfl_xor(A, 1); A += __shfl_xor(A, 2); A += __shfl_xor(A, 4);
    B += __shfl_xor(B, 1); B += __shfl_xor(B, 2); B += __shfl_xor(B, 4);
    // density = sum_j Wd_j*mean_j + Wd'_j*(mean(h^2)_j - mean_j^2) + bd
    float density = A * 0.125f + B * 0.125f - C * (1.0f / 64.0f) + bd[0];

    // hull: sum of mask samples over views
    float hs = msample;
    hs += __shfl_xor(hs, 1); hs += __shfl_xor(hs, 2); hs += __shfl_xor(hs, 4);
    bool hull = hs > ((float)V_ - 0.001f);

    // softmax blend over views
    float mx = lg;
    mx = fmaxf(mx, __shfl_xor(mx, 1));
    mx = fmaxf(mx, __shfl_xor(mx, 2));
    mx = fmaxf(mx, __shfl_xor(mx, 4));
    float e = expf(lg - mx);
    float es = e;
    es += __shfl_xor(es, 1); es += __shfl_xor(es, 2); es += __shfl_xor(es, 4);
    float br = e * rv0, bg = e * rv1, bbl = e * rv2;
    br  += __shfl_xor(br, 1);  br  += __shfl_xor(br, 2);  br  += __shfl_xor(br, 4);
    bg  += __shfl_xor(bg, 1);  bg  += __shfl_xor(bg, 2);  bg  += __shfl_xor(bg, 4);
    bbl += __shfl_xor(bbl, 1); bbl += __shfl_xor(bbl, 2); bbl += __shfl_xor(bbl, 4);

    if (v == 0) {
        float is = 1.0f / es;
        odens[P]      = hull ? density  : 0.f;
        orgb[P*3 + 0] = hull ? br  * is : 0.f;
        orgb[P*3 + 1] = hull ? bg  * is : 0.f;
        orgb[P*3 + 2] = hull ? bbl * is : 0.f;
    }
}

// ---------------------------------------- coarse composite + sample_pdf + merge
__global__ void k_comp_coarse(const float* __restrict__ ray,
                              const float* __restrict__ dens,
                              const float* __restrict__ rgb,
                              float* __restrict__ out,
                              float* __restrict__ fulld) {
    int r = blockIdx.x * blockDim.x + threadIdx.x;
    if (r >= R_) return;
    const float nv = ray[r*8+6], fv = ray[r*8+7];

    float wv[NC_];
    float T = 1.f, c0 = 0.f, c1 = 0.f, c2 = 0.f, cd = 0.f, ca = 0.f;
    for (int s = 0; s < NC_; ++s) {
        float d0 = nv + (fv - nv) * ((s + 0.5f) / NC_);
        float d1 = nv + (fv - nv) * ((s + 1.5f) / NC_);
        float delta = (s == NC_-1) ? 1e10f : (d1 - d0);
        float a = 1.f - expf(-fmaxf(dens[r*NC_+s], 0.f) * delta);
        float wi = a * T;
        wv[s] = wi;
        c0 += wi * rgb[(r*NC_+s)*3+0];
        c1 += wi * rgb[(r*NC_+s)*3+1];
        c2 += wi * rgb[(r*NC_+s)*3+2];
        cd += wi * d0; ca += wi;
        T *= (1.f - a + 1e-10f);
    }
    out[r*3+0] = c0; out[r*3+1] = c1; out[r*3+2] = c2;
    out[3072 + r] = cd;
    out[4096 + r] = ca;

    // ---- sample_pdf(mids, w[1:-1], NF) ----
    float tot = 0.f;
    for (int i = 0; i < 62; ++i) tot += wv[i+1] + 1e-5f;
    float cdf[63];
    cdf[0] = 0.f;
    float run = 0.f;
    for (int i = 0; i < 62; ++i) { run += (wv[i+1] + 1e-5f) / tot; cdf[i+1] = run; }

    float fd[NF_];
    int idx = 1;
    for (int i = 0; i < NF_; ++i) {
        float u = (i + 0.5f) / NF_;
        while (idx < 63 && cdf[idx] <= u) ++idx;
        int below = idx - 1;
        int above = (idx > 62) ? 62 : idx;
        float cA = cdf[below], cB = cdf[above];
        float b0 = nv + (fv - nv) * ((below + 1.0f) / NC_);
        float b1 = nv + (fv - nv) * ((above + 1.0f) / NC_);
        float dnm = cB - cA;
        dnm = (dnm < 1e-5f) ? 1.f : dnm;
        float t = (u - cA) / dnm;
        fd[i] = b0 + t * (b1 - b0);
    }
    float* fl = fulld + r * (NC_ + NF_);
    int a_ = 0, b_ = 0;
    for (int i = 0; i < NC_ + NF_; ++i) {
        float da = (a_ < NC_) ? nv + (fv - nv) * ((a_ + 0.5f) / NC_) : 3.0e38f;
        float db = (b_ < NF_) ? fd[b_] : 3.0e38f;
        if (da <= db) { fl[i] = da; ++a_; } else { fl[i] = db; ++b_; }
    }
}

// ---------------------------------------------------------- fine composite
__global__ void k_comp_fine(const float* __restrict__ fulld,
                            const float* __restrict__ dens,
                            const float* __restrict__ rgb,
                            float* __restrict__ out) {
    int r = blockIdx.x * blockDim.x + threadIdx.x;
    if (r >= R_) return;
    const int S = NC_ + NF_;
    const float* fl = fulld + r * S;
    float T = 1.f, c0 = 0.f, c1 = 0.f, c2 = 0.f, cd = 0.f, ca = 0.f;
    for (int s = 0; s < S; ++s) {
        float d0 = fl[s];
        float delta = (s == S-1) ? 1e10f : (fl[s+1] - d0);
        float a = 1.f - expf(-fmaxf(dens[r*S+s], 0.f) * delta);
        float wi = a * T;
        c0 += wi * rgb[(r*S+s)*3+0];
        c1 += wi * rgb[(r*S+s)*3+1];
        c2 += wi * rgb[(r*S+s)*3+2];
        cd += wi * d0; ca += wi;
        T *= (1.f - a + 1e-10f);
    }
    out[5120 + r*3+0] = c0; out[5120 + r*3+1] = c1; out[5120 + r*3+2] = c2;
    out[8192 + r] = cd;
    out[9216 + r] = ca;
}

// ------------------------------------------------------------------ launch
extern "C" void kernel_launch(void* const* d_in, const int* in_sizes, int n_in,
                              void* d_out, int out_size, void* d_ws, size_t ws_size,
                              hipStream_t stream) {
    const float* ray = (const float*)d_in[0];
    const float* Kin = (const float*)d_in[1];
    const float* Ein = (const float*)d_in[2];
    const float* cam = (const float*)d_in[3];
    const float* shp = (const float*)d_in[4];
    const float* msk = (const float*)d_in[5];
    const float* img = (const float*)d_in[6];
    const float* fea = (const float*)d_in[7];
    const float* cw[8]; for (int i = 0; i < 8; ++i) cw[i] = (const float*)d_in[8+i];
    const float* fw[8]; for (int i = 0; i < 8; ++i) fw[i] = (const float*)d_in[16+i];

    float* ws    = (float*)d_ws;
    float* Pm    = ws;                       // 96
    float* WT    = Pm + 96;                  // 14336
    float* cdens = WT + 14336;               // R*NC            = 65536
    float* crgb  = cdens + R_ * NC_;         // R*NC*3          = 196608
    float* fulld = crgb + R_ * NC_ * 3;      // R*128           = 131072
    float* fdens = fulld + R_ * (NC_+NF_);   // R*128           = 131072
    float* frgb  = fdens + R_ * (NC_+NF_);   // R*128*3         = 393216
    float* pk    = frgb + R_ * (NC_+NF_) * 3;// V*HW*32         = 16777216

    size_t base_floats = (size_t)(pk - ws);
    size_t need_bytes  = (base_floats + (size_t)V_ * HW_ * 32 + 64) * sizeof(float);
    bool packed = (ws_size >= need_bytes);

    float* outp  = (float*)d_out;

    k_computeP<<<1, 96, 0, stream>>>(Kin, Ein, Pm);

    if (packed) {
        k_packW<<<16, 256, 0, stream>>>(cw[0], cw[2], fw[0], fw[2], WT);
        k_packF<<<dim3(W_/64, H_, V_), 256, 0, stream>>>(fea, pk, 0);

        k_mlp<NC_, 0, false, true><<<R_ * NC_ * 8 / 256, 256, 0, stream>>>(
            ray, Pm, cam, shp, msk, img, fea, pk, WT, WT + 3072,
            cw[0], cw[1], cw[2], cw[3], cw[4], cw[5], cw[6], cw[7],
            nullptr, cdens, crgb);

        k_comp_coarse<<<R_ / 256, 256, 0, stream>>>(ray, cdens, crgb, outp, fulld);

        k_packF<<<dim3(W_/64, H_, V_), 256, 0, stream>>>(fea, pk, L_);

        k_mlp<NC_ + NF_, L_, true, true><<<R_ * (NC_+NF_) * 8 / 256, 256, 0, stream>>>(
            ray, Pm, cam, shp, msk, img, fea, pk, WT + 7168, WT + 10240,
            fw[0], fw[1], fw[2], fw[3], fw[4], fw[5], fw[6], fw[7],
            fulld, fdens, frgb);

        k_comp_fine<<<R_ / 256, 256, 0, stream>>>(fulld, fdens, frgb, outp);
    } else {
        k_mlp<NC_, 0, false, false><<<R_ * NC_ * 8 / 256, 256, 0, stream>>>(
            ray, Pm, cam, shp, msk, img, fea, nullptr, nullptr, nullptr,
            cw[0], cw[1], cw[2], cw[3], cw[4], cw[5], cw[6], cw[7],
            nullptr, cdens, crgb);

        k_comp_coarse<<<R_ / 256, 256, 0, stream>>>(ray, cdens, crgb, outp, fulld);

        k_mlp<NC_ + NF_, L_, true, false><<<R_ * (NC_+NF_) * 8 / 256, 256, 0, stream>>>(
            ray, Pm, cam, shp, msk, img, fea, nullptr, nullptr, nullptr,
            fw[0], fw[1], fw[2], fw[3], fw[4], fw[5], fw[6], fw[7],
            fulld, fdens, frgb);

        k_comp_fine<<<R_ / 256, 256, 0, stream>>>(fulld, fdens, frgb, outp);
    }
}